// Round 3
// baseline (5040.011 us; speedup 1.0000x reference)
//
#include <hip/hip_runtime.h>

#define U_CNT 50000
#define I_CNT 100000
#define DIM 64
#define E_CNT 4000000
#define N_CNT (U_CNT + I_CNT)

#define BROWS 128                        // rows per bucket
#define NBKT  ((N_CNT + BROWS - 1) / BROWS)   // 1172
#define NCB   10                         // col blocks: col >> 14 in 0..9
#define NREP  4                          // cursor replication
#define NCNT_TOT (NBKT * NCB * NREP)     // 46880
#define PBLK  ((NCNT_TOT + 255) / 256)   // 184

typedef unsigned long long u64;
typedef unsigned int u32;

__device__ __forceinline__ int edge_key(int r, int c, long e) {
    return (( (r >> 7) * NCB + (c >> 14) ) * NREP) + (int)((e >> 11) & (NREP - 1));
}

// ego = concat(user, item); acc = ego  (float4 vectorized)
__global__ __launch_bounds__(256) void init_kernel(
    const float* __restrict__ user_emb,
    const float* __restrict__ item_emb,
    float* __restrict__ ego,
    float* __restrict__ acc)
{
    long idx = (long)blockIdx.x * blockDim.x + threadIdx.x;   // float4 index
    const long total = (long)N_CNT * DIM / 4;
    if (idx >= total) return;
    long f = idx * 4;
    const long ubound = (long)U_CNT * DIM;
    float4 v;
    if (f < ubound) v = *(const float4*)(user_emb + f);
    else            v = *(const float4*)(item_emb + (f - ubound));
    ((float4*)ego)[idx] = v;
    ((float4*)acc)[idx] = v;
}

__global__ __launch_bounds__(256) void bucket_hist(
    const int* __restrict__ rows, const int* __restrict__ cols,
    int* __restrict__ cnt)
{
    long stride = (long)gridDim.x * blockDim.x;
    for (long e = (long)blockIdx.x * blockDim.x + threadIdx.x; e < E_CNT; e += stride)
        atomicAdd(&cnt[edge_key(rows[e], cols[e], e)], 1);
}

// per-block sums of cnt → partial[b]
__global__ __launch_bounds__(256) void partial_sum_kernel(
    const int* __restrict__ cnt, int* __restrict__ partial)
{
    __shared__ int sm[256];
    int i = blockIdx.x * 256 + threadIdx.x;
    sm[threadIdx.x] = (i < NCNT_TOT) ? cnt[i] : 0;
    __syncthreads();
    for (int off = 128; off > 0; off >>= 1) {
        if (threadIdx.x < off) sm[threadIdx.x] += sm[threadIdx.x + off];
        __syncthreads();
    }
    if (threadIdx.x == 0) partial[blockIdx.x] = sm[0];
}

// exclusive scan of partial[0..PBLK) in one block
__global__ __launch_bounds__(1024) void scan_partial_kernel(int* __restrict__ partial)
{
    __shared__ int sm[1024];
    int tid = threadIdx.x;
    int v = (tid < PBLK) ? partial[tid] : 0;
    sm[tid] = v;
    __syncthreads();
    for (int off = 1; off < 1024; off <<= 1) {
        int t = (tid >= off) ? sm[tid - off] : 0;
        __syncthreads();
        sm[tid] += t;
        __syncthreads();
    }
    if (tid < PBLK) partial[tid] = sm[tid] - v;   // exclusive
}

// final: start[i] = global exclusive prefix; cnt[i] = same (scatter cursor)
__global__ __launch_bounds__(256) void scan_final_kernel(
    int* __restrict__ cnt, const int* __restrict__ partial, int* __restrict__ start)
{
    __shared__ int sm[256];
    int tid = threadIdx.x;
    int i = blockIdx.x * 256 + tid;
    int v = (i < NCNT_TOT) ? cnt[i] : 0;
    sm[tid] = v;
    __syncthreads();
    for (int off = 1; off < 256; off <<= 1) {
        int t = (tid >= off) ? sm[tid - off] : 0;
        __syncthreads();
        sm[tid] += t;
        __syncthreads();
    }
    int excl = partial[blockIdx.x] + sm[tid] - v;
    if (i < NCNT_TOT) {
        start[i] = excl;
        cnt[i] = excl;
        if (i == NCNT_TOT - 1) start[NCNT_TOT] = E_CNT;
    }
}

// pck[pos] = {val:hi32 | row_local<<18 | col}, pos = cursor[key]++
__global__ __launch_bounds__(256) void bucket_scatter(
    const int* __restrict__ rows, const int* __restrict__ cols,
    const float* __restrict__ vals, int* __restrict__ cursor,
    u64* __restrict__ pck)
{
    long stride = (long)gridDim.x * blockDim.x;
    for (long e = (long)blockIdx.x * blockDim.x + threadIdx.x; e < E_CNT; e += stride) {
        int r = rows[e];
        int c = cols[e];
        int p = atomicAdd(&cursor[edge_key(r, c, e)], 1);
        u64 packed = ((u64)__float_as_uint(vals[e]) << 32)
                   | ((u32)(r & (BROWS - 1)) << 18) | (u32)c;
        pck[p] = packed;
    }
}

// One workgroup per 128-row bucket; LDS f32 accumulator; lane = dim.
__global__ __launch_bounds__(256) void spmm_bucket(
    const int* __restrict__ start,
    const u64* __restrict__ pck,
    const float* __restrict__ x,
    float* __restrict__ y,
    float* __restrict__ outacc,
    int last)
{
    __shared__ float acc[BROWS * DIM];     // 32 KB
    const int b = blockIdx.x;
    const int lane = threadIdx.x & 63;
    const int wave = threadIdx.x >> 6;

    for (int i = threadIdx.x; i < BROWS * DIM / 4; i += 256)
        ((float4*)acc)[i] = make_float4(0.f, 0.f, 0.f, 0.f);
    __syncthreads();

    const int s = start[(long)b * NCB * NREP];
    const int e = start[(long)(b + 1) * NCB * NREP];

    for (int base = s + (wave << 6); base < e; base += 256) {
        int cnt = e - base; if (cnt > 64) cnt = 64;
        u64 pk = (base + lane < e) ? pck[base + lane] : 0ULL;
        int j = 0;
        for (; j + 4 <= cnt; j += 4) {
            u64 p0 = __shfl(pk, j);
            u64 p1 = __shfl(pk, j + 1);
            u64 p2 = __shfl(pk, j + 2);
            u64 p3 = __shfl(pk, j + 3);
            float x0 = x[(long)((u32)p0 & 0x3FFFFu) * DIM + lane];
            float x1 = x[(long)((u32)p1 & 0x3FFFFu) * DIM + lane];
            float x2 = x[(long)((u32)p2 & 0x3FFFFu) * DIM + lane];
            float x3 = x[(long)((u32)p3 & 0x3FFFFu) * DIM + lane];
            atomicAdd(&acc[((((u32)p0) >> 18) & (BROWS-1)) * DIM + lane], __uint_as_float((u32)(p0 >> 32)) * x0);
            atomicAdd(&acc[((((u32)p1) >> 18) & (BROWS-1)) * DIM + lane], __uint_as_float((u32)(p1 >> 32)) * x1);
            atomicAdd(&acc[((((u32)p2) >> 18) & (BROWS-1)) * DIM + lane], __uint_as_float((u32)(p2 >> 32)) * x2);
            atomicAdd(&acc[((((u32)p3) >> 18) & (BROWS-1)) * DIM + lane], __uint_as_float((u32)(p3 >> 32)) * x3);
        }
        for (; j < cnt; ++j) {
            u64 p0 = __shfl(pk, j);
            float x0 = x[(long)((u32)p0 & 0x3FFFFu) * DIM + lane];
            atomicAdd(&acc[((((u32)p0) >> 18) & (BROWS-1)) * DIM + lane], __uint_as_float((u32)(p0 >> 32)) * x0);
        }
    }
    __syncthreads();

    const float scale = last ? 0.25f : 1.0f;
    const long base4 = (long)b * (BROWS * DIM / 4);
    const long lim4 = (long)N_CNT * (DIM / 4);
    for (int i = threadIdx.x; i < BROWS * DIM / 4; i += 256) {
        long o4 = base4 + i;
        if (o4 >= lim4) break;
        float4 a = ((const float4*)acc)[i];
        ((float4*)y)[o4] = a;
        float4 t = ((const float4*)outacc)[o4];
        t.x = (t.x + a.x) * scale;
        t.y = (t.y + a.y) * scale;
        t.z = (t.z + a.z) * scale;
        t.w = (t.w + a.w) * scale;
        ((float4*)outacc)[o4] = t;
    }
}

extern "C" void kernel_launch(void* const* d_in, const int* in_sizes, int n_in,
                              void* d_out, int out_size, void* d_ws, size_t ws_size,
                              hipStream_t stream) {
    const float* user_emb = (const float*)d_in[0];
    const float* item_emb = (const float*)d_in[1];
    const int*   rows     = (const int*)d_in[2];
    const int*   cols     = (const int*)d_in[3];
    const float* vals     = (const float*)d_in[4];
    float* outacc = (float*)d_out;               // [N, D]

    char* ws = (char*)d_ws;
    u64*  pck   = (u64*)ws;                       ws += (size_t)E_CNT * 8;
    float* ego  = (float*)ws;                     ws += (size_t)N_CNT * DIM * 4;
    float* nxt  = (float*)ws;                     ws += (size_t)N_CNT * DIM * 4;
    int*  cnt   = (int*)ws;                       ws += (size_t)NCNT_TOT * 4;
    int*  start = (int*)ws;                       ws += (size_t)(NCNT_TOT + 2) * 4;
    int*  partial = (int*)ws;                     ws += 1024 * 4;

    const long total_f4 = (long)N_CNT * DIM / 4;
    const int  vgrid = (int)((total_f4 + 255) / 256);

    hipMemsetAsync(cnt, 0, (size_t)NCNT_TOT * 4, stream);
    init_kernel<<<vgrid, 256, 0, stream>>>(user_emb, item_emb, ego, outacc);

    bucket_hist<<<2048, 256, 0, stream>>>(rows, cols, cnt);
    partial_sum_kernel<<<PBLK, 256, 0, stream>>>(cnt, partial);
    scan_partial_kernel<<<1, 1024, 0, stream>>>(partial);
    scan_final_kernel<<<PBLK, 256, 0, stream>>>(cnt, partial, start);
    bucket_scatter<<<2048, 256, 0, stream>>>(rows, cols, vals, cnt, pck);

    for (int l = 0; l < 3; ++l) {
        spmm_bucket<<<NBKT, 256, 0, stream>>>(start, pck, ego, nxt, outacc, l == 2);
        float* tmp = ego; ego = nxt; nxt = tmp;
    }
}

// Round 4
// 794.144 us; speedup vs baseline: 6.3465x; 6.3465x over previous
//
#include <hip/hip_runtime.h>

#define U_CNT 50000
#define I_CNT 100000
#define DIM 64
#define E_CNT 4000000
#define N_CNT (U_CNT + I_CNT)
#define SCAN_BLK 256
#define NBLK_SCAN ((N_CNT + SCAN_BLK - 1) / SCAN_BLK)   // 586

#define PART_SHIFT 11                      // partition = (row >> 11) & 7 (2048-row stripes)
#define SCAT_CHUNKS 1024
#define CHUNK_E ((E_CNT + SCAT_CHUNKS - 1) / SCAT_CHUNKS)   // 3907

typedef unsigned long long u64;
typedef unsigned int u32;

// ego = concat(user, item); acc = ego  (float4 vectorized; U*D divisible by 4)
__global__ __launch_bounds__(256) void init_kernel(
    const float* __restrict__ user_emb,
    const float* __restrict__ item_emb,
    float* __restrict__ ego,
    float* __restrict__ acc)
{
    long idx = (long)blockIdx.x * blockDim.x + threadIdx.x;   // float4 index
    const long total = (long)N_CNT * DIM / 4;
    if (idx >= total) return;
    long f = idx * 4;
    const long ubound = (long)U_CNT * DIM;
    float4 v;
    if (f < ubound) v = *(const float4*)(user_emb + f);
    else            v = *(const float4*)(item_emb + (f - ubound));
    ((float4*)ego)[idx] = v;
    ((float4*)acc)[idx] = v;
}

// cnt[r]++ for each edge
__global__ __launch_bounds__(256) void hist_kernel(
    const int* __restrict__ rows, int* __restrict__ cnt)
{
    long stride = (long)gridDim.x * blockDim.x;
    for (long e = (long)blockIdx.x * blockDim.x + threadIdx.x; e < E_CNT; e += stride)
        atomicAdd(&cnt[rows[e]], 1);
}

// per-block sums of cnt → partial[b]
__global__ __launch_bounds__(SCAN_BLK) void partial_sum_kernel(
    const int* __restrict__ cnt, int* __restrict__ partial)
{
    __shared__ int sm[SCAN_BLK];
    int i = blockIdx.x * SCAN_BLK + threadIdx.x;
    sm[threadIdx.x] = (i < N_CNT) ? cnt[i] : 0;
    __syncthreads();
    for (int off = SCAN_BLK / 2; off > 0; off >>= 1) {
        if (threadIdx.x < off) sm[threadIdx.x] += sm[threadIdx.x + off];
        __syncthreads();
    }
    if (threadIdx.x == 0) partial[blockIdx.x] = sm[0];
}

// exclusive scan of partial[0..NBLK_SCAN) in one block
__global__ __launch_bounds__(1024) void scan_partial_kernel(int* __restrict__ partial)
{
    __shared__ int sm[1024];
    int tid = threadIdx.x;
    int v = (tid < NBLK_SCAN) ? partial[tid] : 0;
    sm[tid] = v;
    __syncthreads();
    for (int off = 1; off < 1024; off <<= 1) {
        int t = (tid >= off) ? sm[tid - off] : 0;
        __syncthreads();
        sm[tid] += t;
        __syncthreads();
    }
    if (tid < NBLK_SCAN) partial[tid] = sm[tid] - v;   // exclusive
}

// final scan: row_start[i] = global exclusive prefix; cnt[i] = same (scatter cursor)
__global__ __launch_bounds__(SCAN_BLK) void scan_final_kernel(
    int* __restrict__ cnt, const int* __restrict__ partial, int* __restrict__ row_start)
{
    __shared__ int sm[SCAN_BLK];
    int tid = threadIdx.x;
    int i = blockIdx.x * SCAN_BLK + tid;
    int v = (i < N_CNT) ? cnt[i] : 0;
    sm[tid] = v;
    __syncthreads();
    for (int off = 1; off < SCAN_BLK; off <<= 1) {
        int t = (tid >= off) ? sm[tid - off] : 0;
        __syncthreads();
        sm[tid] += t;
        __syncthreads();
    }
    int excl = partial[blockIdx.x] + sm[tid] - v;
    if (i < N_CNT) {
        row_start[i] = excl;
        cnt[i] = excl;                       // becomes scatter cursor
        if (i == N_CNT - 1) row_start[N_CNT] = E_CNT;
    }
}

// XCD-affinity scatter: block b handles row-partition (b&7) over edge chunk (b>>3).
// All pck writes for a row stripe come from one XCD -> its L2 accumulates full lines.
__global__ __launch_bounds__(256) void scatter_part(
    const int* __restrict__ rows, const int* __restrict__ cols,
    const float* __restrict__ vals, int* __restrict__ cursor,
    u64* __restrict__ pck)
{
    const int part  = blockIdx.x & 7;
    const int chunk = blockIdx.x >> 3;
    long e0 = (long)chunk * CHUNK_E;
    long e1 = e0 + CHUNK_E; if (e1 > E_CNT) e1 = E_CNT;
    for (long e = e0 + threadIdx.x; e < e1; e += 256) {
        int r = rows[e];
        if (((r >> PART_SHIFT) & 7) == part) {
            int p = atomicAdd(&cursor[r], 1);
            u64 packed = ((u64)__float_as_uint(vals[e]) << 32) | (u32)cols[e];
            pck[p] = packed;
        }
    }
}

// Pull CSR SpMM, one wave per row. lane = (group g=lane>>4, dim-quad q=lane&15).
// Group g processes edges j+g via float4 gathers (4 edges / VMEM instr);
// butterfly shfl_xor combines the 4 group-partials. Fused acc update.
__global__ __launch_bounds__(256) void spmm_csr(
    const int* __restrict__ row_start,
    const u64* __restrict__ pck,
    const float* __restrict__ x,
    float* __restrict__ y,
    float* __restrict__ outacc,
    int last)
{
    const int lane = threadIdx.x & 63;
    const int g    = lane >> 4;
    const int q    = lane & 15;
    int r = (int)(((long)blockIdx.x * blockDim.x + threadIdx.x) >> 6);
    if (r >= N_CNT) return;
    int s = row_start[r];
    int e = row_start[r + 1];
    float4 acc = make_float4(0.f, 0.f, 0.f, 0.f);
    for (int base = s; base < e; base += 64) {
        int cnt = e - base; if (cnt > 64) cnt = 64;
        u64 pk = (base + lane < e) ? pck[base + lane] : 0ULL;
        for (int j = 0; j < cnt; j += 4) {
            int je = j + g;
            u64 p = __shfl(pk, je);
            if (je < cnt) {
                const float4 xv = *(const float4*)(x + (long)((u32)p) * DIM + (q << 2));
                float v = __uint_as_float((u32)(p >> 32));
                acc.x = fmaf(v, xv.x, acc.x);
                acc.y = fmaf(v, xv.y, acc.y);
                acc.z = fmaf(v, xv.z, acc.z);
                acc.w = fmaf(v, xv.w, acc.w);
            }
        }
    }
    // combine groups: lanes {q, q+16, q+32, q+48} hold partials of the same dims
    for (int off = 16; off < 64; off <<= 1) {
        acc.x += __shfl_xor(acc.x, off);
        acc.y += __shfl_xor(acc.y, off);
        acc.z += __shfl_xor(acc.z, off);
        acc.w += __shfl_xor(acc.w, off);
    }
    if (g == 0) {
        long o4 = (long)r * (DIM / 4) + q;
        ((float4*)y)[o4] = acc;
        float4 t = ((const float4*)outacc)[o4];
        float scale = last ? 0.25f : 1.0f;
        t.x = (t.x + acc.x) * scale;
        t.y = (t.y + acc.y) * scale;
        t.z = (t.z + acc.z) * scale;
        t.w = (t.w + acc.w) * scale;
        ((float4*)outacc)[o4] = t;
    }
}

extern "C" void kernel_launch(void* const* d_in, const int* in_sizes, int n_in,
                              void* d_out, int out_size, void* d_ws, size_t ws_size,
                              hipStream_t stream) {
    const float* user_emb = (const float*)d_in[0];
    const float* item_emb = (const float*)d_in[1];
    const int*   rows     = (const int*)d_in[2];
    const int*   cols     = (const int*)d_in[3];
    const float* vals     = (const float*)d_in[4];
    float* outacc = (float*)d_out;               // [N, D]

    char* ws = (char*)d_ws;
    u64*  pck       = (u64*)ws;                   ws += (size_t)E_CNT * 8;
    float* ego      = (float*)ws;                 ws += (size_t)N_CNT * DIM * 4;
    float* nxt      = (float*)ws;                 ws += (size_t)N_CNT * DIM * 4;
    int*  cnt       = (int*)ws;                   ws += (size_t)N_CNT * 4;
    int*  row_start = (int*)ws;                   ws += (size_t)(N_CNT + 2) * 4;
    int*  partial   = (int*)ws;                   ws += 1024 * 4;

    const long total_f4 = (long)N_CNT * DIM / 4;
    const int  vgrid = (int)((total_f4 + 255) / 256);

    hipMemsetAsync(cnt, 0, (size_t)N_CNT * 4, stream);
    init_kernel<<<vgrid, 256, 0, stream>>>(user_emb, item_emb, ego, outacc);

    hist_kernel<<<2048, 256, 0, stream>>>(rows, cnt);
    partial_sum_kernel<<<NBLK_SCAN, SCAN_BLK, 0, stream>>>(cnt, partial);
    scan_partial_kernel<<<1, 1024, 0, stream>>>(partial);
    scan_final_kernel<<<NBLK_SCAN, SCAN_BLK, 0, stream>>>(cnt, partial, row_start);
    scatter_part<<<SCAT_CHUNKS * 8, 256, 0, stream>>>(rows, cols, vals, cnt, pck);

    const int spmm_grid = (N_CNT * 64 + 255) / 256;   // one wave per row
    for (int l = 0; l < 3; ++l) {
        spmm_csr<<<spmm_grid, 256, 0, stream>>>(row_start, pck, ego, nxt, outacc, l == 2);
        float* tmp = ego; ego = nxt; nxt = tmp;
    }
}

// Round 5
// 624.373 us; speedup vs baseline: 8.0721x; 1.2719x over previous
//
#include <hip/hip_runtime.h>

#define U_CNT 50000
#define I_CNT 100000
#define DIM 64
#define E_CNT 4000000
#define N_CNT (U_CNT + I_CNT)
#define SCAN_BLK 256
#define NBLK_SCAN ((N_CNT + SCAN_BLK - 1) / SCAN_BLK)   // 586

#define NBUK ((N_CNT + 255) / 256)        // 586 row-buckets of 256 rows
#define CHUNK_A 8192                       // edges per block in phase A
#define NBLK_A ((E_CNT + CHUNK_A - 1) / CHUNK_A)   // 489

typedef unsigned long long u64;
typedef unsigned int u32;
typedef unsigned short u16;

__device__ __forceinline__ float bf2f(u16 h) {
    return __uint_as_float((u32)h << 16);
}
__device__ __forceinline__ u16 f2bf(float f) {
    u32 u = __float_as_uint(f);
    return (u16)((u + 0x7FFFu + ((u >> 16) & 1u)) >> 16);   // RNE
}

// ego(bf16) = concat(user,item); acc(f32) = same
__global__ __launch_bounds__(256) void init_kernel(
    const float* __restrict__ user_emb,
    const float* __restrict__ item_emb,
    u16* __restrict__ ego,
    float* __restrict__ acc)
{
    long idx = (long)blockIdx.x * blockDim.x + threadIdx.x;   // quad index
    const long total = (long)N_CNT * DIM / 4;
    if (idx >= total) return;
    long f = idx * 4;
    const long ubound = (long)U_CNT * DIM;
    float4 v;
    if (f < ubound) v = *(const float4*)(user_emb + f);
    else            v = *(const float4*)(item_emb + (f - ubound));
    ((float4*)acc)[idx] = v;
    ushort4 b;
    b.x = f2bf(v.x); b.y = f2bf(v.y); b.z = f2bf(v.z); b.w = f2bf(v.w);
    *(ushort4*)(ego + f) = b;
}

// cnt[r]++ for each edge
__global__ __launch_bounds__(256) void hist_kernel(
    const int* __restrict__ rows, int* __restrict__ cnt)
{
    long stride = (long)gridDim.x * blockDim.x;
    for (long e = (long)blockIdx.x * blockDim.x + threadIdx.x; e < E_CNT; e += stride)
        atomicAdd(&cnt[rows[e]], 1);
}

__global__ __launch_bounds__(SCAN_BLK) void partial_sum_kernel(
    const int* __restrict__ cnt, int* __restrict__ partial)
{
    __shared__ int sm[SCAN_BLK];
    int i = blockIdx.x * SCAN_BLK + threadIdx.x;
    sm[threadIdx.x] = (i < N_CNT) ? cnt[i] : 0;
    __syncthreads();
    for (int off = SCAN_BLK / 2; off > 0; off >>= 1) {
        if (threadIdx.x < off) sm[threadIdx.x] += sm[threadIdx.x + off];
        __syncthreads();
    }
    if (threadIdx.x == 0) partial[blockIdx.x] = sm[0];
}

__global__ __launch_bounds__(1024) void scan_partial_kernel(int* __restrict__ partial)
{
    __shared__ int sm[1024];
    int tid = threadIdx.x;
    int v = (tid < NBLK_SCAN) ? partial[tid] : 0;
    sm[tid] = v;
    __syncthreads();
    for (int off = 1; off < 1024; off <<= 1) {
        int t = (tid >= off) ? sm[tid - off] : 0;
        __syncthreads();
        sm[tid] += t;
        __syncthreads();
    }
    if (tid < NBLK_SCAN) partial[tid] = sm[tid] - v;   // exclusive
}

// row_start[i] = global exclusive prefix; cnt[i] = same (row scatter cursor)
__global__ __launch_bounds__(SCAN_BLK) void scan_final_kernel(
    int* __restrict__ cnt, const int* __restrict__ partial, int* __restrict__ row_start)
{
    __shared__ int sm[SCAN_BLK];
    int tid = threadIdx.x;
    int i = blockIdx.x * SCAN_BLK + tid;
    int v = (i < N_CNT) ? cnt[i] : 0;
    sm[tid] = v;
    __syncthreads();
    for (int off = 1; off < SCAN_BLK; off <<= 1) {
        int t = (tid >= off) ? sm[tid - off] : 0;
        __syncthreads();
        sm[tid] += t;
        __syncthreads();
    }
    int excl = partial[blockIdx.x] + sm[tid] - v;
    if (i < N_CNT) {
        row_start[i] = excl;
        cnt[i] = excl;
        if (i == N_CNT - 1) row_start[N_CNT] = E_CNT;
    }
}

// bucket_cursor[b] = row_start[b << 8]
__global__ __launch_bounds__(1024) void init_bucket_cursor(
    const int* __restrict__ row_start, int* __restrict__ bucket_cursor)
{
    int b = threadIdx.x;
    if (b < NBUK) bucket_cursor[b] = row_start[b << 8];
}

// Phase A: LDS-aggregated bucket scatter.
// pck1[pos] = {val:f32 hi | row_local<<18 | col}, bucket-grouped, block-contiguous runs.
__global__ __launch_bounds__(256) void bucket_scatter(
    const int* __restrict__ rows, const int* __restrict__ cols,
    const float* __restrict__ vals, int* __restrict__ bucket_cursor,
    u64* __restrict__ pck1)
{
    __shared__ int hist[NBUK];
    __shared__ int base[NBUK];
    const int tid = threadIdx.x;
    for (int i = tid; i < NBUK; i += 256) hist[i] = 0;
    __syncthreads();

    long e0 = (long)blockIdx.x * CHUNK_A;
    long e1 = e0 + CHUNK_A; if (e1 > E_CNT) e1 = E_CNT;

    for (long e = e0 + tid; e < e1; e += 256)
        atomicAdd(&hist[rows[e] >> 8], 1);
    __syncthreads();

    for (int i = tid; i < NBUK; i += 256) {
        int h = hist[i];
        base[i] = h ? atomicAdd(&bucket_cursor[i], h) : 0;
        hist[i] = 0;
    }
    __syncthreads();

    for (long e = e0 + tid; e < e1; e += 256) {
        int r = rows[e];
        int b = r >> 8;
        int k = atomicAdd(&hist[b], 1);
        u64 packed = ((u64)__float_as_uint(vals[e]) << 32)
                   | ((u32)(r & 255) << 18) | (u32)cols[e];
        pck1[base[b] + k] = packed;
    }
}

// Phase B: one block per bucket; exact row position via cnt cursors.
// Destination slice is contiguous (~55 KB) -> write frontier L2-resident.
__global__ __launch_bounds__(256) void row_scatter(
    const int* __restrict__ row_start, const u64* __restrict__ pck1,
    int* __restrict__ cursor, u64* __restrict__ pck)
{
    const int b = blockIdx.x;
    const int s = row_start[b << 8];
    const int e = (b == NBUK - 1) ? E_CNT : row_start[(b + 1) << 8];
    for (int i = s + threadIdx.x; i < e; i += 256) {
        u64 v = pck1[i];
        int r = (b << 8) | (int)((v >> 18) & 255);
        int p = atomicAdd(&cursor[r], 1);
        pck[p] = v;                       // row_local bits ignored downstream
    }
}

// Pull CSR SpMM (bf16 x), one wave per row. lane = (group g=lane>>4, quad q=lane&15).
// Group g handles edges j+g; 8-B bf16x4 gather per edge; butterfly combine.
__global__ __launch_bounds__(256) void spmm_csr(
    const int* __restrict__ row_start,
    const u64* __restrict__ pck,
    const u16* __restrict__ x,
    u16* __restrict__ y,
    float* __restrict__ outacc,
    int last)
{
    const int lane = threadIdx.x & 63;
    const int g    = lane >> 4;
    const int q    = lane & 15;
    int r = (int)(((long)blockIdx.x * blockDim.x + threadIdx.x) >> 6);
    if (r >= N_CNT) return;
    int s = row_start[r];
    int e = row_start[r + 1];
    float4 acc = make_float4(0.f, 0.f, 0.f, 0.f);
    for (int base = s; base < e; base += 64) {
        int cnt = e - base; if (cnt > 64) cnt = 64;
        u64 pk = (base + lane < e) ? pck[base + lane] : 0ULL;
        for (int j = 0; j < cnt; j += 4) {
            int je = j + g;
            u64 p = __shfl(pk, je);
            if (je < cnt) {
                int c = (int)((u32)p & 0x3FFFFu);
                ushort4 xb = *(const ushort4*)(x + (long)c * DIM + (q << 2));
                float v = __uint_as_float((u32)(p >> 32));
                acc.x = fmaf(v, bf2f(xb.x), acc.x);
                acc.y = fmaf(v, bf2f(xb.y), acc.y);
                acc.z = fmaf(v, bf2f(xb.z), acc.z);
                acc.w = fmaf(v, bf2f(xb.w), acc.w);
            }
        }
    }
    for (int off = 16; off < 64; off <<= 1) {
        acc.x += __shfl_xor(acc.x, off);
        acc.y += __shfl_xor(acc.y, off);
        acc.z += __shfl_xor(acc.z, off);
        acc.w += __shfl_xor(acc.w, off);
    }
    if (g == 0) {
        long o = (long)r * DIM + (q << 2);
        ushort4 yb;
        yb.x = f2bf(acc.x); yb.y = f2bf(acc.y); yb.z = f2bf(acc.z); yb.w = f2bf(acc.w);
        *(ushort4*)(y + o) = yb;
        float4 t = *(const float4*)(outacc + o);
        float scale = last ? 0.25f : 1.0f;
        t.x = (t.x + acc.x) * scale;
        t.y = (t.y + acc.y) * scale;
        t.z = (t.z + acc.z) * scale;
        t.w = (t.w + acc.w) * scale;
        *(float4*)(outacc + o) = t;
    }
}

extern "C" void kernel_launch(void* const* d_in, const int* in_sizes, int n_in,
                              void* d_out, int out_size, void* d_ws, size_t ws_size,
                              hipStream_t stream) {
    const float* user_emb = (const float*)d_in[0];
    const float* item_emb = (const float*)d_in[1];
    const int*   rows     = (const int*)d_in[2];
    const int*   cols     = (const int*)d_in[3];
    const float* vals     = (const float*)d_in[4];
    float* outacc = (float*)d_out;               // [N, D] f32

    char* ws = (char*)d_ws;
    u64*  pck1      = (u64*)ws;                   ws += (size_t)E_CNT * 8;
    u64*  pck       = (u64*)ws;                   ws += (size_t)E_CNT * 8;
    u16*  ego       = (u16*)ws;                   ws += (size_t)N_CNT * DIM * 2;
    u16*  nxt       = (u16*)ws;                   ws += (size_t)N_CNT * DIM * 2;
    int*  cnt       = (int*)ws;                   ws += (size_t)N_CNT * 4;
    int*  row_start = (int*)ws;                   ws += (size_t)(N_CNT + 2) * 4;
    int*  partial   = (int*)ws;                   ws += 1024 * 4;
    int*  bucket_cursor = (int*)ws;               ws += (size_t)(NBUK + 4) * 4;

    const long total_f4 = (long)N_CNT * DIM / 4;
    const int  vgrid = (int)((total_f4 + 255) / 256);

    hipMemsetAsync(cnt, 0, (size_t)N_CNT * 4, stream);
    init_kernel<<<vgrid, 256, 0, stream>>>(user_emb, item_emb, ego, outacc);

    hist_kernel<<<2048, 256, 0, stream>>>(rows, cnt);
    partial_sum_kernel<<<NBLK_SCAN, SCAN_BLK, 0, stream>>>(cnt, partial);
    scan_partial_kernel<<<1, 1024, 0, stream>>>(partial);
    scan_final_kernel<<<NBLK_SCAN, SCAN_BLK, 0, stream>>>(cnt, partial, row_start);
    init_bucket_cursor<<<1, 1024, 0, stream>>>(row_start, bucket_cursor);

    bucket_scatter<<<NBLK_A, 256, 0, stream>>>(rows, cols, vals, bucket_cursor, pck1);
    row_scatter<<<NBUK, 256, 0, stream>>>(row_start, pck1, cnt, pck);

    const int spmm_grid = (N_CNT * 64 + 255) / 256;   // one wave per row
    for (int l = 0; l < 3; ++l) {
        spmm_csr<<<spmm_grid, 256, 0, stream>>>(row_start, pck, ego, nxt, outacc, l == 2);
        u16* tmp = ego; ego = nxt; nxt = tmp;
    }
}

// Round 6
// 451.835 us; speedup vs baseline: 11.1545x; 1.3819x over previous
//
#include <hip/hip_runtime.h>

#define U_CNT 50000
#define I_CNT 100000
#define DIM 64
#define E_CNT 4000000
#define N_CNT (U_CNT + I_CNT)

#define NBUK ((N_CNT + 255) / 256)                 // 586 row-buckets of 256 rows
#define CAP  8192                                  // pck1 slots per bucket (mean 6827, +16 sigma)
#define CHUNK_A 8192                               // edges per block in scatter
#define NBLK_A ((E_CNT + CHUNK_A - 1) / CHUNK_A)   // 489

typedef unsigned long long u64;
typedef unsigned int u32;
typedef unsigned short u16;

__device__ __forceinline__ float bf2f(u16 h) {
    return __uint_as_float((u32)h << 16);
}
__device__ __forceinline__ u16 f2bf(float f) {
    u32 u = __float_as_uint(f);
    return (u16)((u + 0x7FFFu + ((u >> 16) & 1u)) >> 16);   // RNE
}

// ego(bf16) = concat(user,item); acc(f32) = same
__global__ __launch_bounds__(256) void init_kernel(
    const float* __restrict__ user_emb,
    const float* __restrict__ item_emb,
    u16* __restrict__ ego,
    float* __restrict__ acc)
{
    long idx = (long)blockIdx.x * blockDim.x + threadIdx.x;   // quad index
    const long total = (long)N_CNT * DIM / 4;
    if (idx >= total) return;
    long f = idx * 4;
    const long ubound = (long)U_CNT * DIM;
    float4 v;
    if (f < ubound) v = *(const float4*)(user_emb + f);
    else            v = *(const float4*)(item_emb + (f - ubound));
    ((float4*)acc)[idx] = v;
    ushort4 b;
    b.x = f2bf(v.x); b.y = f2bf(v.y); b.z = f2bf(v.z); b.w = f2bf(v.w);
    *(ushort4*)(ego + f) = b;
}

// LDS-aggregated bucket scatter into padded per-bucket slots (no prior count pass).
// pck1[b*CAP + k] = {val:f32 hi | row_local<<18 | col}
__global__ __launch_bounds__(256) void bucket_scatter(
    const int* __restrict__ rows, const int* __restrict__ cols,
    const float* __restrict__ vals, int* __restrict__ bucket_cursor,
    u64* __restrict__ pck1)
{
    __shared__ int hist[NBUK];
    __shared__ int base[NBUK];
    const int tid = threadIdx.x;
    for (int i = tid; i < NBUK; i += 256) hist[i] = 0;
    __syncthreads();

    long e0 = (long)blockIdx.x * CHUNK_A;
    long e1 = e0 + CHUNK_A; if (e1 > E_CNT) e1 = E_CNT;

    for (long e = e0 + tid; e < e1; e += 256)
        atomicAdd(&hist[rows[e] >> 8], 1);
    __syncthreads();

    for (int i = tid; i < NBUK; i += 256) {
        int h = hist[i];
        base[i] = h ? atomicAdd(&bucket_cursor[i], h) : 0;
        hist[i] = 0;
    }
    __syncthreads();

    for (long e = e0 + tid; e < e1; e += 256) {
        int r = rows[e];
        int b = r >> 8;
        int k = base[b] + atomicAdd(&hist[b], 1);
        if (k < CAP) {
            u64 packed = ((u64)__float_as_uint(vals[e]) << 32)
                       | ((u32)(r & 255) << 18) | (u32)cols[e];
            pck1[(long)b * CAP + k] = packed;
        }
    }
}

// exclusive scan of the 586 bucket counts -> bucket_base
__global__ __launch_bounds__(1024) void bucket_scan(
    const int* __restrict__ bucket_cursor, int* __restrict__ bucket_base)
{
    __shared__ int sm[1024];
    int tid = threadIdx.x;
    int c = (tid < NBUK) ? bucket_cursor[tid] : 0;
    int v = (c > CAP) ? CAP : c;
    sm[tid] = v;
    __syncthreads();
    for (int off = 1; off < 1024; off <<= 1) {
        int t = (tid >= off) ? sm[tid - off] : 0;
        __syncthreads();
        sm[tid] += t;
        __syncthreads();
    }
    if (tid < NBUK) bucket_base[tid] = sm[tid] - v;   // exclusive
}

// One block per bucket: in-LDS counting sort by row_local.
// Emits row-sorted compact pck AND row_start directly.
__global__ __launch_bounds__(256) void bucket_sort(
    const u64* __restrict__ pck1,
    const int* __restrict__ bucket_cursor,
    const int* __restrict__ bucket_base,
    u64* __restrict__ pck,
    int* __restrict__ row_start)
{
    __shared__ int h[256];
    __shared__ int sm[256];
    __shared__ int cur[256];
    const int b   = blockIdx.x;
    const int tid = threadIdx.x;
    int cnt = bucket_cursor[b]; if (cnt > CAP) cnt = CAP;
    const int S = bucket_base[b];
    const u64* src = pck1 + (long)b * CAP;

    h[tid] = 0;
    __syncthreads();
    for (int i = tid; i < cnt; i += 256)
        atomicAdd(&h[(int)((src[i] >> 18) & 255)], 1);
    __syncthreads();

    int v = h[tid];
    sm[tid] = v;
    __syncthreads();
    for (int off = 1; off < 256; off <<= 1) {
        int t = (tid >= off) ? sm[tid - off] : 0;
        __syncthreads();
        sm[tid] += t;
        __syncthreads();
    }
    int excl = sm[tid] - v;
    cur[tid] = excl;
    int idx = (b << 8) + tid;
    if (idx <= N_CNT) row_start[idx] = S + excl;
    __syncthreads();

    for (int i = tid; i < cnt; i += 256) {
        u64 pv = src[i];
        int rl = (int)((pv >> 18) & 255);
        int p = atomicAdd(&cur[rl], 1);
        pck[S + p] = pv;
    }
}

// Pull CSR SpMM (bf16 x), one wave per row. lane = (group g=lane>>4, quad q=lane&15).
// Group g handles edges j+g; 8-B bf16x4 gather per edge; butterfly combine.
__global__ __launch_bounds__(256) void spmm_csr(
    const int* __restrict__ row_start,
    const u64* __restrict__ pck,
    const u16* __restrict__ x,
    u16* __restrict__ y,
    float* __restrict__ outacc,
    int last)
{
    const int lane = threadIdx.x & 63;
    const int g    = lane >> 4;
    const int q    = lane & 15;
    int r = (int)(((long)blockIdx.x * blockDim.x + threadIdx.x) >> 6);
    if (r >= N_CNT) return;
    int s = row_start[r];
    int e = row_start[r + 1];
    float4 acc = make_float4(0.f, 0.f, 0.f, 0.f);
    int base = s;
    for (; base + 64 <= e; base += 64) {          // full chunks: no bounds checks
        u64 pk = pck[base + lane];
        #pragma unroll
        for (int j = 0; j < 64; j += 4) {
            u64 p = __shfl(pk, j + g);
            int c = (int)((u32)p & 0x3FFFFu);
            ushort4 xb = *(const ushort4*)(x + (long)c * DIM + (q << 2));
            float v = __uint_as_float((u32)(p >> 32));
            acc.x = fmaf(v, bf2f(xb.x), acc.x);
            acc.y = fmaf(v, bf2f(xb.y), acc.y);
            acc.z = fmaf(v, bf2f(xb.z), acc.z);
            acc.w = fmaf(v, bf2f(xb.w), acc.w);
        }
    }
    if (base < e) {                               // tail chunk
        int cnt = e - base;
        u64 pk = (base + lane < e) ? pck[base + lane] : 0ULL;
        for (int j = 0; j < cnt; j += 4) {
            int je = j + g;
            u64 p = __shfl(pk, je);
            if (je < cnt) {
                int c = (int)((u32)p & 0x3FFFFu);
                ushort4 xb = *(const ushort4*)(x + (long)c * DIM + (q << 2));
                float v = __uint_as_float((u32)(p >> 32));
                acc.x = fmaf(v, bf2f(xb.x), acc.x);
                acc.y = fmaf(v, bf2f(xb.y), acc.y);
                acc.z = fmaf(v, bf2f(xb.z), acc.z);
                acc.w = fmaf(v, bf2f(xb.w), acc.w);
            }
        }
    }
    for (int off = 16; off < 64; off <<= 1) {
        acc.x += __shfl_xor(acc.x, off);
        acc.y += __shfl_xor(acc.y, off);
        acc.z += __shfl_xor(acc.z, off);
        acc.w += __shfl_xor(acc.w, off);
    }
    if (g == 0) {
        long o = (long)r * DIM + (q << 2);
        ushort4 yb;
        yb.x = f2bf(acc.x); yb.y = f2bf(acc.y); yb.z = f2bf(acc.z); yb.w = f2bf(acc.w);
        *(ushort4*)(y + o) = yb;
        float4 t = *(const float4*)(outacc + o);
        float scale = last ? 0.25f : 1.0f;
        t.x = (t.x + acc.x) * scale;
        t.y = (t.y + acc.y) * scale;
        t.z = (t.z + acc.z) * scale;
        t.w = (t.w + acc.w) * scale;
        *(float4*)(outacc + o) = t;
    }
}

extern "C" void kernel_launch(void* const* d_in, const int* in_sizes, int n_in,
                              void* d_out, int out_size, void* d_ws, size_t ws_size,
                              hipStream_t stream) {
    const float* user_emb = (const float*)d_in[0];
    const float* item_emb = (const float*)d_in[1];
    const int*   rows     = (const int*)d_in[2];
    const int*   cols     = (const int*)d_in[3];
    const float* vals     = (const float*)d_in[4];
    float* outacc = (float*)d_out;               // [N, D] f32

    char* ws = (char*)d_ws;
    u64*  pck  = (u64*)ws;                        ws += (size_t)E_CNT * 8;
    // pck1 (padded, dead after bucket_sort) aliases ego/nxt (written after it)
    u64*  pck1 = (u64*)ws;
    u16*  ego  = (u16*)ws;
    u16*  nxt  = ego + (size_t)N_CNT * DIM;
    {
        size_t a = (size_t)NBUK * CAP * 8;                 // 38,404,096
        size_t b = (size_t)N_CNT * DIM * 2 * 2;            // 38,400,000
        ws += (a > b) ? a : b;
    }
    int* row_start     = (int*)ws;                ws += (size_t)(N_CNT + 16) * 4;
    int* bucket_cursor = (int*)ws;                ws += 1024 * 4;
    int* bucket_base   = (int*)ws;                ws += 1024 * 4;

    hipMemsetAsync(bucket_cursor, 0, (size_t)NBUK * 4, stream);

    bucket_scatter<<<NBLK_A, 256, 0, stream>>>(rows, cols, vals, bucket_cursor, pck1);
    bucket_scan<<<1, 1024, 0, stream>>>(bucket_cursor, bucket_base);
    bucket_sort<<<NBUK, 256, 0, stream>>>(pck1, bucket_cursor, bucket_base, pck, row_start);

    const long total_f4 = (long)N_CNT * DIM / 4;
    const int  vgrid = (int)((total_f4 + 255) / 256);
    init_kernel<<<vgrid, 256, 0, stream>>>(user_emb, item_emb, ego, outacc);

    const int spmm_grid = (N_CNT * 64 + 255) / 256;   // one wave per row
    for (int l = 0; l < 3; ++l) {
        spmm_csr<<<spmm_grid, 256, 0, stream>>>(row_start, pck, ego, nxt, outacc, l == 2);
        u16* tmp = ego; ego = nxt; nxt = tmp;
    }
}

// Round 7
// 388.422 us; speedup vs baseline: 12.9756x; 1.1633x over previous
//
#include <hip/hip_runtime.h>

#define U_CNT 50000
#define I_CNT 100000
#define DIM 64
#define E_CNT 4000000
#define N_CNT (U_CNT + I_CNT)

#define NBUK ((N_CNT + 255) / 256)                 // 586 row-buckets of 256 rows
#define CAP  8192                                  // pck1 slots per bucket (mean 6827)
#define CHUNK_A 8192                               // edges per block in scatter
#define NBLK_A ((E_CNT + CHUNK_A - 1) / CHUNK_A)   // 489

typedef unsigned long long u64;
typedef unsigned int u32;
typedef unsigned short u16;

__device__ __forceinline__ u16 f2bf(float f) {
    u32 u = __float_as_uint(f);
    return (u16)((u + 0x7FFFu + ((u >> 16) & 1u)) >> 16);   // RNE
}

// ego(bf16) = concat(user,item)   (acc is produced by spmm pass 1)
__global__ __launch_bounds__(256) void init_kernel(
    const float* __restrict__ user_emb,
    const float* __restrict__ item_emb,
    u16* __restrict__ ego)
{
    long idx = (long)blockIdx.x * blockDim.x + threadIdx.x;   // quad index
    const long total = (long)N_CNT * DIM / 4;
    if (idx >= total) return;
    long f = idx * 4;
    const long ubound = (long)U_CNT * DIM;
    float4 v;
    if (f < ubound) v = *(const float4*)(user_emb + f);
    else            v = *(const float4*)(item_emb + (f - ubound));
    ushort4 b;
    b.x = f2bf(v.x); b.y = f2bf(v.y); b.z = f2bf(v.z); b.w = f2bf(v.w);
    *(ushort4*)(ego + f) = b;
}

// LDS-aggregated bucket scatter into padded per-bucket slots.
// pck1[b*CAP + k] = {val:f32 hi | row_local<<18 | col}
__global__ __launch_bounds__(256) void bucket_scatter(
    const int* __restrict__ rows, const int* __restrict__ cols,
    const float* __restrict__ vals, int* __restrict__ bucket_cursor,
    u64* __restrict__ pck1)
{
    __shared__ int hist[NBUK];
    __shared__ int base[NBUK];
    const int tid = threadIdx.x;
    for (int i = tid; i < NBUK; i += 256) hist[i] = 0;
    __syncthreads();

    long e0 = (long)blockIdx.x * CHUNK_A;
    long e1 = e0 + CHUNK_A; if (e1 > E_CNT) e1 = E_CNT;

    for (long e = e0 + tid; e < e1; e += 256)
        atomicAdd(&hist[rows[e] >> 8], 1);
    __syncthreads();

    for (int i = tid; i < NBUK; i += 256) {
        int h = hist[i];
        base[i] = h ? atomicAdd(&bucket_cursor[i], h) : 0;
        hist[i] = 0;
    }
    __syncthreads();

    for (long e = e0 + tid; e < e1; e += 256) {
        int r = rows[e];
        int b = r >> 8;
        int k = base[b] + atomicAdd(&hist[b], 1);
        if (k < CAP) {
            u64 packed = ((u64)__float_as_uint(vals[e]) << 32)
                       | ((u32)(r & 255) << 18) | (u32)cols[e];
            pck1[(long)b * CAP + k] = packed;
        }
    }
}

// exclusive scan of the 586 bucket counts -> bucket_base
__global__ __launch_bounds__(1024) void bucket_scan(
    const int* __restrict__ bucket_cursor, int* __restrict__ bucket_base)
{
    __shared__ int sm[1024];
    int tid = threadIdx.x;
    int c = (tid < NBUK) ? bucket_cursor[tid] : 0;
    int v = (c > CAP) ? CAP : c;
    sm[tid] = v;
    __syncthreads();
    for (int off = 1; off < 1024; off <<= 1) {
        int t = (tid >= off) ? sm[tid - off] : 0;
        __syncthreads();
        sm[tid] += t;
        __syncthreads();
    }
    if (tid < NBUK) bucket_base[tid] = sm[tid] - v;   // exclusive
}

// One block per bucket: in-LDS counting sort by row_local.
// Emits row-sorted compact pck AND row_start directly.
__global__ __launch_bounds__(256) void bucket_sort(
    const u64* __restrict__ pck1,
    const int* __restrict__ bucket_cursor,
    const int* __restrict__ bucket_base,
    u64* __restrict__ pck,
    int* __restrict__ row_start)
{
    __shared__ int h[256];
    __shared__ int sm[256];
    __shared__ int cur[256];
    const int b   = blockIdx.x;
    const int tid = threadIdx.x;
    int cnt = bucket_cursor[b]; if (cnt > CAP) cnt = CAP;
    const int S = bucket_base[b];
    const u64* src = pck1 + (long)b * CAP;

    h[tid] = 0;
    __syncthreads();
    for (int i = tid; i < cnt; i += 256)
        atomicAdd(&h[(int)((src[i] >> 18) & 255)], 1);
    __syncthreads();

    int v = h[tid];
    sm[tid] = v;
    __syncthreads();
    for (int off = 1; off < 256; off <<= 1) {
        int t = (tid >= off) ? sm[tid - off] : 0;
        __syncthreads();
        sm[tid] += t;
        __syncthreads();
    }
    int excl = sm[tid] - v;
    cur[tid] = excl;
    int idx = (b << 8) + tid;
    if (idx <= N_CNT) row_start[idx] = S + excl;
    __syncthreads();

    for (int i = tid; i < cnt; i += 256) {
        u64 pv = src[i];
        int rl = (int)((pv >> 18) & 255);
        int p = atomicAdd(&cur[rl], 1);
        pck[S + p] = pv;
    }
}

// Pull CSR SpMM (bf16 x), one wave per row.
// lane = (group g=lane>>3, dim-octet h=lane&7); group g handles edge (j*8+g):
// 16-B dwordx4 gather (8 bf16 dims) per edge; 3-step butterfly combine over g.
// mode 0: acc_out = bf16(x[r]) + l      (no acc read)
// mode 1: acc_out = acc + l
// mode 2: acc_out = (acc + l) * 0.25,   no y write
__global__ __launch_bounds__(256) void spmm_csr(
    const int* __restrict__ row_start,
    const u64* __restrict__ pck,
    const u16* __restrict__ x,
    u16* __restrict__ y,
    float* __restrict__ outacc,
    int mode)
{
    const int lane = threadIdx.x & 63;
    const int g    = lane >> 3;
    const int h    = lane & 7;
    int r = (int)(((long)blockIdx.x * blockDim.x + threadIdx.x) >> 6);
    if (r >= N_CNT) return;
    int s = row_start[r];
    int e = row_start[r + 1];
    float a0 = 0.f, a1 = 0.f, a2 = 0.f, a3 = 0.f;
    float a4 = 0.f, a5 = 0.f, a6 = 0.f, a7 = 0.f;

#define EDGE_BODY(P)                                                        \
    {                                                                       \
        u32 c = (u32)(P) & 0x3FFFFu;                                        \
        float v = __uint_as_float((u32)((P) >> 32));                        \
        const uint4 xb = *(const uint4*)(x + ((long)c << 6) + (h << 3));    \
        a0 = fmaf(v, __uint_as_float(xb.x << 16),          a0);             \
        a1 = fmaf(v, __uint_as_float(xb.x & 0xFFFF0000u),  a1);             \
        a2 = fmaf(v, __uint_as_float(xb.y << 16),          a2);             \
        a3 = fmaf(v, __uint_as_float(xb.y & 0xFFFF0000u),  a3);             \
        a4 = fmaf(v, __uint_as_float(xb.z << 16),          a4);             \
        a5 = fmaf(v, __uint_as_float(xb.z & 0xFFFF0000u),  a5);             \
        a6 = fmaf(v, __uint_as_float(xb.w << 16),          a6);             \
        a7 = fmaf(v, __uint_as_float(xb.w & 0xFFFF0000u),  a7);             \
    }

    for (int base = s; base < e; base += 64) {
        int cnt = e - base; if (cnt > 64) cnt = 64;
        u64 pk = (base + lane < e) ? pck[base + lane] : 0ULL;
        if (cnt == 64) {
            #pragma unroll
            for (int j = 0; j < 8; ++j) {
                u64 p = __shfl(pk, (j << 3) + g);
                EDGE_BODY(p)
            }
        } else {
            for (int j = 0; (j << 3) < cnt; ++j) {
                int ei = (j << 3) + g;
                u64 p = __shfl(pk, ei);
                if (ei < cnt) EDGE_BODY(p)
            }
        }
    }
#undef EDGE_BODY

    // combine groups: lanes with equal h hold the same dim octet
    #pragma unroll
    for (int off = 8; off < 64; off <<= 1) {
        a0 += __shfl_xor(a0, off);
        a1 += __shfl_xor(a1, off);
        a2 += __shfl_xor(a2, off);
        a3 += __shfl_xor(a3, off);
        a4 += __shfl_xor(a4, off);
        a5 += __shfl_xor(a5, off);
        a6 += __shfl_xor(a6, off);
        a7 += __shfl_xor(a7, off);
    }

    if (g == 0) {
        long o = ((long)r << 6) + (h << 3);
        if (mode < 2) {
            ushort4 y0, y1;
            y0.x = f2bf(a0); y0.y = f2bf(a1); y0.z = f2bf(a2); y0.w = f2bf(a3);
            y1.x = f2bf(a4); y1.y = f2bf(a5); y1.z = f2bf(a6); y1.w = f2bf(a7);
            *(ushort4*)(y + o)     = y0;
            *(ushort4*)(y + o + 4) = y1;
        }
        float4 t0, t1;
        if (mode == 0) {
            const uint4 xb = *(const uint4*)(x + o);   // ego bf16 -> f32
            t0.x = __uint_as_float(xb.x << 16)         + a0;
            t0.y = __uint_as_float(xb.x & 0xFFFF0000u) + a1;
            t0.z = __uint_as_float(xb.y << 16)         + a2;
            t0.w = __uint_as_float(xb.y & 0xFFFF0000u) + a3;
            t1.x = __uint_as_float(xb.z << 16)         + a4;
            t1.y = __uint_as_float(xb.z & 0xFFFF0000u) + a5;
            t1.z = __uint_as_float(xb.w << 16)         + a6;
            t1.w = __uint_as_float(xb.w & 0xFFFF0000u) + a7;
        } else {
            t0 = *(const float4*)(outacc + o);
            t1 = *(const float4*)(outacc + o + 4);
            t0.x += a0; t0.y += a1; t0.z += a2; t0.w += a3;
            t1.x += a4; t1.y += a5; t1.z += a6; t1.w += a7;
            if (mode == 2) {
                t0.x *= 0.25f; t0.y *= 0.25f; t0.z *= 0.25f; t0.w *= 0.25f;
                t1.x *= 0.25f; t1.y *= 0.25f; t1.z *= 0.25f; t1.w *= 0.25f;
            }
        }
        *(float4*)(outacc + o)     = t0;
        *(float4*)(outacc + o + 4) = t1;
    }
}

extern "C" void kernel_launch(void* const* d_in, const int* in_sizes, int n_in,
                              void* d_out, int out_size, void* d_ws, size_t ws_size,
                              hipStream_t stream) {
    const float* user_emb = (const float*)d_in[0];
    const float* item_emb = (const float*)d_in[1];
    const int*   rows     = (const int*)d_in[2];
    const int*   cols     = (const int*)d_in[3];
    const float* vals     = (const float*)d_in[4];
    float* outacc = (float*)d_out;               // [N, D] f32

    char* ws = (char*)d_ws;
    u64*  pck  = (u64*)ws;                        ws += (size_t)E_CNT * 8;
    // pck1 (padded, dead after bucket_sort) aliases ego/nxt (written after it)
    u64*  pck1 = (u64*)ws;
    u16*  ego  = (u16*)ws;
    u16*  nxt  = ego + (size_t)N_CNT * DIM;
    {
        size_t a = (size_t)NBUK * CAP * 8;                 // 38,404,096
        size_t b = (size_t)N_CNT * DIM * 2 * 2;            // 38,400,000
        ws += (a > b) ? a : b;
    }
    int* row_start     = (int*)ws;                ws += (size_t)(N_CNT + 16) * 4;
    int* bucket_cursor = (int*)ws;                ws += 1024 * 4;
    int* bucket_base   = (int*)ws;                ws += 1024 * 4;

    hipMemsetAsync(bucket_cursor, 0, (size_t)NBUK * 4, stream);

    bucket_scatter<<<NBLK_A, 256, 0, stream>>>(rows, cols, vals, bucket_cursor, pck1);
    bucket_scan<<<1, 1024, 0, stream>>>(bucket_cursor, bucket_base);
    bucket_sort<<<NBUK, 256, 0, stream>>>(pck1, bucket_cursor, bucket_base, pck, row_start);

    const long total_f4 = (long)N_CNT * DIM / 4;
    const int  vgrid = (int)((total_f4 + 255) / 256);
    init_kernel<<<vgrid, 256, 0, stream>>>(user_emb, item_emb, ego);

    const int spmm_grid = (N_CNT * 64 + 255) / 256;   // one wave per row
    for (int l = 0; l < 3; ++l) {
        spmm_csr<<<spmm_grid, 256, 0, stream>>>(row_start, pck, ego, nxt, outacc, l);
        u16* tmp = ego; ego = nxt; nxt = tmp;
    }
}

// Round 8
// 379.031 us; speedup vs baseline: 13.2971x; 1.0248x over previous
//
#include <hip/hip_runtime.h>

#define U_CNT 50000
#define I_CNT 100000
#define DIM 64
#define E_CNT 4000000
#define N_CNT (U_CNT + I_CNT)

#define BROWS 512                                  // rows per bucket
#define NBUK ((N_CNT + BROWS - 1) / BROWS)         // 293
#define CAP  16384                                 // pck1 slots per bucket (mean 13653)
#define CHUNK_A 8192                               // edges per block in scatter
#define NBLK_A ((E_CNT + CHUNK_A - 1) / CHUNK_A)   // 489
#define EPT (CHUNK_A / 512)                        // 16 edges per thread

typedef unsigned long long u64;
typedef unsigned int u32;
typedef unsigned short u16;

__device__ __forceinline__ u16 f2bf(float f) {
    u32 u = __float_as_uint(f);
    return (u16)((u + 0x7FFFu + ((u >> 16) & 1u)) >> 16);   // RNE
}

// ego(bf16) = concat(user,item)   (acc is produced by spmm pass 1)
__global__ __launch_bounds__(256) void init_kernel(
    const float* __restrict__ user_emb,
    const float* __restrict__ item_emb,
    u16* __restrict__ ego)
{
    long idx = (long)blockIdx.x * blockDim.x + threadIdx.x;   // quad index
    const long total = (long)N_CNT * DIM / 4;
    if (idx >= total) return;
    long f = idx * 4;
    const long ubound = (long)U_CNT * DIM;
    float4 v;
    if (f < ubound) v = *(const float4*)(user_emb + f);
    else            v = *(const float4*)(item_emb + (f - ubound));
    ushort4 b;
    b.x = f2bf(v.x); b.y = f2bf(v.y); b.z = f2bf(v.z); b.w = f2bf(v.w);
    *(ushort4*)(ego + f) = b;
}

// LDS-aggregated bucket scatter into padded per-bucket slots.
// Pass1: rank via LDS hist, saved in registers (b<<22 | rl<<13 | k).
// Pass2: one global reservation per (block,bucket).
// Pass3: write pck1[b*CAP + base[b]+k] = {val:f32 hi | row_local<<18 | col}
__global__ __launch_bounds__(512) void bucket_scatter(
    const int* __restrict__ rows, const int* __restrict__ cols,
    const float* __restrict__ vals, int* __restrict__ bucket_cursor,
    u64* __restrict__ pck1)
{
    __shared__ int hist[NBUK];
    __shared__ int base[NBUK];
    const int tid = threadIdx.x;
    if (tid < NBUK) hist[tid] = 0;
    __syncthreads();

    long e0 = (long)blockIdx.x * CHUNK_A;
    long e1 = e0 + CHUNK_A; if (e1 > E_CNT) e1 = E_CNT;

    u32 saved[EPT];
    int n = 0;
    for (long e = e0 + tid; e < e1; e += 512) {
        int r = rows[e];
        int b = r >> 9;
        int k = atomicAdd(&hist[b], 1);
        saved[n++] = ((u32)b << 22) | ((u32)(r & (BROWS - 1)) << 13) | (u32)k;
    }
    __syncthreads();

    if (tid < NBUK) {
        int h = hist[tid];
        base[tid] = h ? atomicAdd(&bucket_cursor[tid], h) : 0;
    }
    __syncthreads();

    n = 0;
    for (long e = e0 + tid; e < e1; e += 512) {
        u32 s = saved[n++];
        int b  = (int)(s >> 22);
        int rl = (int)((s >> 13) & (BROWS - 1));
        int k  = (int)(s & 8191);
        int pos = base[b] + k;
        if (pos < CAP) {
            u64 packed = ((u64)__float_as_uint(vals[e]) << 32)
                       | ((u32)rl << 18) | (u32)cols[e];
            pck1[(long)b * CAP + pos] = packed;
        }
    }
}

// exclusive scan of the 293 bucket counts -> bucket_base
__global__ __launch_bounds__(1024) void bucket_scan(
    const int* __restrict__ bucket_cursor, int* __restrict__ bucket_base)
{
    __shared__ int sm[1024];
    int tid = threadIdx.x;
    int c = (tid < NBUK) ? bucket_cursor[tid] : 0;
    int v = (c > CAP) ? CAP : c;
    sm[tid] = v;
    __syncthreads();
    for (int off = 1; off < 1024; off <<= 1) {
        int t = (tid >= off) ? sm[tid - off] : 0;
        __syncthreads();
        sm[tid] += t;
        __syncthreads();
    }
    if (tid < NBUK) bucket_base[tid] = sm[tid] - v;   // exclusive
}

// One block per bucket: in-LDS counting sort by row_local (512-way).
// Emits row-sorted compact pck AND row_start directly.
__global__ __launch_bounds__(512) void bucket_sort(
    const u64* __restrict__ pck1,
    const int* __restrict__ bucket_cursor,
    const int* __restrict__ bucket_base,
    u64* __restrict__ pck,
    int* __restrict__ row_start)
{
    __shared__ int h[BROWS];
    __shared__ int sm[BROWS];
    __shared__ int cur[BROWS];
    const int b   = blockIdx.x;
    const int tid = threadIdx.x;
    int cnt = bucket_cursor[b]; if (cnt > CAP) cnt = CAP;
    const int S = bucket_base[b];
    const u64* src = pck1 + (long)b * CAP;

    h[tid] = 0;
    __syncthreads();
    for (int i = tid; i < cnt; i += 512)
        atomicAdd(&h[(int)((src[i] >> 18) & (BROWS - 1))], 1);
    __syncthreads();

    int v = h[tid];
    sm[tid] = v;
    __syncthreads();
    for (int off = 1; off < BROWS; off <<= 1) {
        int t = (tid >= off) ? sm[tid - off] : 0;
        __syncthreads();
        sm[tid] += t;
        __syncthreads();
    }
    int excl = sm[tid] - v;
    cur[tid] = excl;
    int idx = (b << 9) + tid;
    if (idx <= N_CNT) row_start[idx] = S + excl;
    __syncthreads();

    for (int i = tid; i < cnt; i += 512) {
        u64 pv = src[i];
        int rl = (int)((pv >> 18) & (BROWS - 1));
        int p = atomicAdd(&cur[rl], 1);
        pck[S + p] = pv;
    }
}

// Pull CSR SpMM (bf16 x), one wave per row.
// lane = (group g=lane>>3, dim-octet h=lane&7); group g handles edge (j*8+g):
// 16-B dwordx4 gather (8 bf16 dims) per edge; 3-step butterfly combine over g.
// mode 0: acc_out = bf16(x[r]) + l      (no acc read)
// mode 1: acc_out = acc + l
// mode 2: acc_out = (acc + l) * 0.25,   no y write
__global__ __launch_bounds__(256) void spmm_csr(
    const int* __restrict__ row_start,
    const u64* __restrict__ pck,
    const u16* __restrict__ x,
    u16* __restrict__ y,
    float* __restrict__ outacc,
    int mode)
{
    const int lane = threadIdx.x & 63;
    const int g    = lane >> 3;
    const int h    = lane & 7;
    int r = (int)(((long)blockIdx.x * blockDim.x + threadIdx.x) >> 6);
    if (r >= N_CNT) return;
    int s = row_start[r];
    int e = row_start[r + 1];
    float a0 = 0.f, a1 = 0.f, a2 = 0.f, a3 = 0.f;
    float a4 = 0.f, a5 = 0.f, a6 = 0.f, a7 = 0.f;

#define EDGE_BODY(P)                                                        \
    {                                                                       \
        u32 c = (u32)(P) & 0x3FFFFu;                                        \
        float v = __uint_as_float((u32)((P) >> 32));                        \
        const uint4 xb = *(const uint4*)(x + ((long)c << 6) + (h << 3));    \
        a0 = fmaf(v, __uint_as_float(xb.x << 16),          a0);             \
        a1 = fmaf(v, __uint_as_float(xb.x & 0xFFFF0000u),  a1);             \
        a2 = fmaf(v, __uint_as_float(xb.y << 16),          a2);             \
        a3 = fmaf(v, __uint_as_float(xb.y & 0xFFFF0000u),  a3);             \
        a4 = fmaf(v, __uint_as_float(xb.z << 16),          a4);             \
        a5 = fmaf(v, __uint_as_float(xb.z & 0xFFFF0000u),  a5);             \
        a6 = fmaf(v, __uint_as_float(xb.w << 16),          a6);             \
        a7 = fmaf(v, __uint_as_float(xb.w & 0xFFFF0000u),  a7);             \
    }

    for (int base = s; base < e; base += 64) {
        int cnt = e - base; if (cnt > 64) cnt = 64;
        u64 pk = (base + lane < e) ? pck[base + lane] : 0ULL;
        if (cnt == 64) {
            #pragma unroll
            for (int j = 0; j < 8; ++j) {
                u64 p = __shfl(pk, (j << 3) + g);
                EDGE_BODY(p)
            }
        } else {
            for (int j = 0; (j << 3) < cnt; ++j) {
                int ei = (j << 3) + g;
                u64 p = __shfl(pk, ei);
                if (ei < cnt) EDGE_BODY(p)
            }
        }
    }
#undef EDGE_BODY

    // combine groups: lanes with equal h hold the same dim octet
    #pragma unroll
    for (int off = 8; off < 64; off <<= 1) {
        a0 += __shfl_xor(a0, off);
        a1 += __shfl_xor(a1, off);
        a2 += __shfl_xor(a2, off);
        a3 += __shfl_xor(a3, off);
        a4 += __shfl_xor(a4, off);
        a5 += __shfl_xor(a5, off);
        a6 += __shfl_xor(a6, off);
        a7 += __shfl_xor(a7, off);
    }

    if (g == 0) {
        long o = ((long)r << 6) + (h << 3);
        if (mode < 2) {
            ushort4 y0, y1;
            y0.x = f2bf(a0); y0.y = f2bf(a1); y0.z = f2bf(a2); y0.w = f2bf(a3);
            y1.x = f2bf(a4); y1.y = f2bf(a5); y1.z = f2bf(a6); y1.w = f2bf(a7);
            *(ushort4*)(y + o)     = y0;
            *(ushort4*)(y + o + 4) = y1;
        }
        float4 t0, t1;
        if (mode == 0) {
            const uint4 xb = *(const uint4*)(x + o);   // ego bf16 -> f32
            t0.x = __uint_as_float(xb.x << 16)         + a0;
            t0.y = __uint_as_float(xb.x & 0xFFFF0000u) + a1;
            t0.z = __uint_as_float(xb.y << 16)         + a2;
            t0.w = __uint_as_float(xb.y & 0xFFFF0000u) + a3;
            t1.x = __uint_as_float(xb.z << 16)         + a4;
            t1.y = __uint_as_float(xb.z & 0xFFFF0000u) + a5;
            t1.z = __uint_as_float(xb.w << 16)         + a6;
            t1.w = __uint_as_float(xb.w & 0xFFFF0000u) + a7;
        } else {
            t0 = *(const float4*)(outacc + o);
            t1 = *(const float4*)(outacc + o + 4);
            t0.x += a0; t0.y += a1; t0.z += a2; t0.w += a3;
            t1.x += a4; t1.y += a5; t1.z += a6; t1.w += a7;
            if (mode == 2) {
                t0.x *= 0.25f; t0.y *= 0.25f; t0.z *= 0.25f; t0.w *= 0.25f;
                t1.x *= 0.25f; t1.y *= 0.25f; t1.z *= 0.25f; t1.w *= 0.25f;
            }
        }
        *(float4*)(outacc + o)     = t0;
        *(float4*)(outacc + o + 4) = t1;
    }
}

extern "C" void kernel_launch(void* const* d_in, const int* in_sizes, int n_in,
                              void* d_out, int out_size, void* d_ws, size_t ws_size,
                              hipStream_t stream) {
    const float* user_emb = (const float*)d_in[0];
    const float* item_emb = (const float*)d_in[1];
    const int*   rows     = (const int*)d_in[2];
    const int*   cols     = (const int*)d_in[3];
    const float* vals     = (const float*)d_in[4];
    float* outacc = (float*)d_out;               // [N, D] f32

    char* ws = (char*)d_ws;
    u64*  pck  = (u64*)ws;                        ws += (size_t)E_CNT * 8;
    // pck1 (padded, dead after bucket_sort) aliases ego/nxt (written after it)
    u64*  pck1 = (u64*)ws;
    u16*  ego  = (u16*)ws;
    u16*  nxt  = ego + (size_t)N_CNT * DIM;
    {
        size_t a = (size_t)NBUK * CAP * 8;                 // 38,404,096
        size_t b = (size_t)N_CNT * DIM * 2 * 2;            // 38,400,000
        ws += (a > b) ? a : b;
    }
    int* row_start     = (int*)ws;                ws += (size_t)(N_CNT + 16) * 4;
    int* bucket_cursor = (int*)ws;                ws += 1024 * 4;
    int* bucket_base   = (int*)ws;                ws += 1024 * 4;

    hipMemsetAsync(bucket_cursor, 0, (size_t)NBUK * 4, stream);

    bucket_scatter<<<NBLK_A, 512, 0, stream>>>(rows, cols, vals, bucket_cursor, pck1);
    bucket_scan<<<1, 1024, 0, stream>>>(bucket_cursor, bucket_base);
    bucket_sort<<<NBUK, 512, 0, stream>>>(pck1, bucket_cursor, bucket_base, pck, row_start);

    const long total_f4 = (long)N_CNT * DIM / 4;
    const int  vgrid = (int)((total_f4 + 255) / 256);
    init_kernel<<<vgrid, 256, 0, stream>>>(user_emb, item_emb, ego);

    const int spmm_grid = (N_CNT * 64 + 255) / 256;   // one wave per row
    for (int l = 0; l < 3; ++l) {
        spmm_csr<<<spmm_grid, 256, 0, stream>>>(row_start, pck, ego, nxt, outacc, l);
        u16* tmp = ego; ego = nxt; nxt = tmp;
    }
}